// Round 6
// baseline (299.524 us; speedup 1.0000x reference)
//
#include <hip/hip_runtime.h>
#include <math.h>

// Round 12: R11 resubmitted with the compile error fixed.
// __builtin_nontemporal_store rejects HIP's float4 (a HIP_vector_type class);
// use a native clang ext_vector_type(4) alias for the NT stores instead.
// Everything else identical to R11:
//  - R10 architecture (4 res/thread, 2 waves/chain, no spill)
//  - reads: 9 aligned dwordx4/thread; window-edge params via __shfl_up of the
//    neighbor's tail registers (scalar fallback only for lane0/wave1)
//  - output via non-temporal dwordx4 stores (write-once data, skip L2 alloc)

#define LCH 512

typedef float f32x4 __attribute__((ext_vector_type(4)));

struct Xf { float r[9]; float t[3]; };

__device__ __forceinline__ Xf xf_compose(const Xf& A, const Xf& B) {
  Xf C;
#pragma unroll
  for (int i = 0; i < 3; ++i) {
    float a0 = A.r[3*i+0], a1 = A.r[3*i+1], a2 = A.r[3*i+2];
    C.r[3*i+0] = a0*B.r[0] + a1*B.r[3] + a2*B.r[6];
    C.r[3*i+1] = a0*B.r[1] + a1*B.r[4] + a2*B.r[7];
    C.r[3*i+2] = a0*B.r[2] + a1*B.r[5] + a2*B.r[8];
    C.t[i]     = a0*B.t[0] + a1*B.t[1] + a2*B.t[2] + A.t[i];
  }
  return C;
}

// P := P o Delta(theta, len, tau), sparsity-aware (~31 FMA).
__device__ __forceinline__ void xf_step(Xf& P, float theta, float len, float tau) {
  float st, ct, sx, cx;
  __sincosf(theta, &st, &ct);
  __sincosf(tau, &sx, &cx);
  float ux = -ct, uy = cx*st, uz = sx*st;      // delta col0 (= d_local / L)
  float v0 = -st, v1 = -ct*cx, v2 = -ct*sx;    // delta col1; col2 = (0,-sx,cx)
  float c00 = P.r[0]*ux + P.r[1]*uy + P.r[2]*uz;
  float c10 = P.r[3]*ux + P.r[4]*uy + P.r[5]*uz;
  float c20 = P.r[6]*ux + P.r[7]*uy + P.r[8]*uz;
  float c01 = P.r[0]*v0 + P.r[1]*v1 + P.r[2]*v2;
  float c11 = P.r[3]*v0 + P.r[4]*v1 + P.r[5]*v2;
  float c21 = P.r[6]*v0 + P.r[7]*v1 + P.r[8]*v2;
  float c02 = P.r[2]*cx - P.r[1]*sx;
  float c12 = P.r[5]*cx - P.r[4]*sx;
  float c22 = P.r[8]*cx - P.r[7]*sx;
  P.t[0] += len*c00; P.t[1] += len*c10; P.t[2] += len*c20;
  P.r[0]=c00; P.r[1]=c01; P.r[2]=c02;
  P.r[3]=c10; P.r[4]=c11; P.r[5]=c12;
  P.r[6]=c20; P.r[7]=c21; P.r[8]=c22;
}

__device__ __forceinline__ void xf_set_delta(Xf& P, float theta, float len, float tau) {
  float st, ct, sx, cx;
  __sincosf(theta, &st, &ct);
  __sincosf(tau, &sx, &cx);
  float ux = -ct, uy = cx*st, uz = sx*st;
  P.r[0]=ux; P.r[1]=-st;    P.r[2]=0.f;
  P.r[3]=uy; P.r[4]=-ct*cx; P.r[5]=-sx;
  P.r[6]=uz; P.r[7]=-ct*sx; P.r[8]=cx;
  P.t[0]=len*ux; P.t[1]=len*uy; P.t[2]=len*uz;
}

__device__ __forceinline__ void xf_identity(Xf& A) {
  A.r[0]=1.f; A.r[1]=0.f; A.r[2]=0.f;
  A.r[3]=0.f; A.r[4]=1.f; A.r[5]=0.f;
  A.r[6]=0.f; A.r[7]=0.f; A.r[8]=1.f;
  A.t[0]=0.f; A.t[1]=0.f; A.t[2]=0.f;
}

__device__ __forceinline__ Xf xf_shfl_up(const Xf& P, int d) {
  Xf O;
#pragma unroll
  for (int i = 0; i < 9; ++i) O.r[i] = __shfl_up(P.r[i], d, 64);
#pragma unroll
  for (int i = 0; i < 3; ++i) O.t[i] = __shfl_up(P.t[i], d, 64);
  return O;
}

// replay matvec for output float f (0..35) of this thread; f compile-time.
#define REP(f) (A.r[3*((f)%3)+0]*sx[(f)/3] + A.r[3*((f)%3)+1]*sy[(f)/3] \
              + A.r[3*((f)%3)+2]*sz[(f)/3] + A.t[(f)%3])

__global__ __launch_bounds__(128) void nerf_r12_kernel(
    const float* __restrict__ g_phi, const float* __restrict__ g_psi,
    const float* __restrict__ g_omg, const float* __restrict__ g_bl,
    const float* __restrict__ g_ba, float* __restrict__ g_out)
{
  __shared__ float s_tot[12];           // wave-0 inclusive total

  const int t    = threadIdx.x;         // 0..127
  const int lane = t & 63;
  const int wave = t >> 6;
  const int chain = blockIdx.x;

  const float* phir = g_phi + (size_t)chain * LCH;
  const float* psir = g_psi + (size_t)chain * LCH;
  const float* omgr = g_omg + (size_t)chain * LCH;
  const float* blr  = g_bl  + (size_t)chain * (LCH*3);
  const float* bar  = g_ba  + (size_t)chain * (LCH*3);

  const int j4  = 4 * t;     // window is residues [4t-1 .. 4t+2]
  const int b12 = 12 * t;

  // ---- 9 aligned dwordx4 loads per thread ----
  float4 vps = *(const float4*)(psir + j4);      // psi[4t .. 4t+3]
  float4 vom = *(const float4*)(omgr + j4);      // omg[4t .. 4t+3]
  float4 vph = *(const float4*)(phir + j4);      // phi[4t .. 4t+3] (phi[r+1] set)
  float4 l0  = *(const float4*)(blr + b12);      // bl[12t   .. 12t+3]
  float4 l1  = *(const float4*)(blr + b12 + 4);  // bl[12t+4 .. 12t+7]
  float4 l2  = *(const float4*)(blr + b12 + 8);  // bl[12t+8 .. 12t+11]
  float4 a0  = *(const float4*)(bar + b12);
  float4 a1  = *(const float4*)(bar + b12 + 4);
  float4 a2  = *(const float4*)(bar + b12 + 8);

  // ---- window-edge params from neighbor's tail registers ----
  float psN  = __shfl_up(vps.w, 1, 64);   // psi[4t-1]
  float omN  = __shfl_up(vom.w, 1, 64);   // omg[4t-1]
  float blN0 = __shfl_up(l2.y, 1, 64);    // bl[12t-3]
  float blN1 = __shfl_up(l2.z, 1, 64);    // bl[12t-2]
  float blN2 = __shfl_up(l2.w, 1, 64);    // bl[12t-1]
  float baN0 = __shfl_up(a2.y, 1, 64);
  float baN1 = __shfl_up(a2.z, 1, 64);
  float baN2 = __shfl_up(a2.w, 1, 64);
  if (lane == 0 && t != 0) {              // cross-wave edge (t == 64 only)
    psN  = psir[j4 - 1];
    omN  = omgr[j4 - 1];
    blN0 = blr[b12 - 3]; blN1 = blr[b12 - 2]; blN2 = blr[b12 - 1];
    baN0 = bar[b12 - 3]; baN1 = bar[b12 - 2]; baN2 = bar[b12 - 1];
  }
  // (t==0: edge values are junk; they feed only the discarded pre-roll steps)

  float PS[4] = { psN, vps.x, vps.y, vps.z };
  float OM[4] = { omN, vom.x, vom.y, vom.z };
  float PH[4] = { vph.x, vph.y, vph.z, vph.w };
  float BL[12] = { blN0, blN1, blN2, l0.x, l0.y, l0.z, l0.w,
                   l1.x, l1.y, l1.z, l1.w, l2.x };
  float BA[12] = { baN0, baN1, baN2, a0.x, a0.y, a0.z, a0.w,
                   a1.x, a1.y, a1.z, a1.w, a2.x };

  // ---- Phase A: 12 serial steps, stash partial translations ----
  // step a of window residue m: a=0 (N): theta=ba1 L=bl2 tau=psi
  //   a=1 (CA): theta=ba2 L=bl0 tau=omega;  a=2 (C): theta=ba0 L=bl1 tau=phi[r+1]
  Xf P;
  float sx[12], sy[12], sz[12];
#pragma unroll
  for (int k = 0; k < 12; ++k) {
    const int m = k / 3, a = k - 3*m;   // compile-time after unroll
    float th, ln, ta;
    if (a == 0)      { th = BA[3*m+1]; ln = BL[3*m+2]; ta = PS[m]; }
    else if (a == 1) { th = BA[3*m+2]; ln = BL[3*m+0]; ta = OM[m]; }
    else             { th = BA[3*m+0]; ln = BL[3*m+1]; ta = PH[m]; }
    if (k == 0) xf_set_delta(P, th, ln, ta);
    else        xf_step(P, th, ln, ta);
    sx[k] = P.t[0]; sy[k] = P.t[1]; sz[k] = P.t[2];
    if (k == 2 && t == 0) xf_identity(P);  // discard t=0 pre-roll
  }

  // ---- intra-wave inclusive scan (non-commutative) ----
#pragma unroll
  for (int d = 1; d < 64; d <<= 1) {
    Xf O = xf_shfl_up(P, d);
    if (lane >= d) P = xf_compose(O, P);
  }

  // wave-0 total -> LDS for wave 1
  if (wave == 0 && lane == 63) {
#pragma unroll
    for (int i = 0; i < 9; ++i) s_tot[i] = P.r[i];
#pragma unroll
    for (int i = 0; i < 3; ++i) s_tot[9+i] = P.t[i];
  }
  Xf E = xf_shfl_up(P, 1);   // within-wave exclusive (junk for lane 0)
  __syncthreads();

  // ---- prefix transform A = I0 [o W0total] [o E] ----
  Xf A;
  {
    const float ax=17.047f, ay=14.099f, az=3.625f;
    const float bx_=16.967f, by_=12.784f, bz_=4.338f;
    const float cx_=15.685f, cy_=12.755f, cz_=5.133f;
    float abx=bx_-ax, aby=by_-ay, abz=bz_-az;
    float vx=cx_-bx_, vy=cy_-by_, vz=cz_-bz_;
    float vn = sqrtf(vx*vx+vy*vy+vz*vz) + 1e-8f;
    vx/=vn; vy/=vn; vz/=vn;
    float crx = aby*vz - abz*vy;
    float cry = abz*vx - abx*vz;
    float crz = abx*vy - aby*vx;
    float cn = sqrtf(crx*crx+cry*cry+crz*crz) + 1e-8f;
    float nx=crx/cn, ny=cry/cn, nz=crz/cn;
    float mx = ny*vz - nz*vy;
    float my = nz*vx - nx*vz;
    float mz = nx*vy - ny*vx;
    A.r[0]=vx; A.r[1]=mx; A.r[2]=nx;
    A.r[3]=vy; A.r[4]=my; A.r[5]=ny;
    A.r[6]=vz; A.r[7]=mz; A.r[8]=nz;
    A.t[0]=cx_; A.t[1]=cy_; A.t[2]=cz_;
  }
  if (wave == 1) {
    Xf T;
#pragma unroll
    for (int i = 0; i < 9; ++i) T.r[i] = s_tot[i];
#pragma unroll
    for (int i = 0; i < 3; ++i) T.t[i] = s_tot[9+i];
    A = xf_compose(A, T);
  }
  if (lane > 0) A = xf_compose(A, E);

  // ---- fused replay + non-temporal dwordx4 stores ----
  // thread t owns output floats [36t, 36t+36) of the chain row.
  float* orow = g_out + (size_t)chain * 4608 + 36 * t;
#pragma unroll
  for (int q = 0; q < 9; ++q) {
    f32x4 v;
    v.x = REP(4*q + 0);
    v.y = REP(4*q + 1);
    v.z = REP(4*q + 2);
    v.w = REP(4*q + 3);
    if (t == 0) {   // init block replaces the 3 junk pre-roll atoms (f 0..8)
      if (q == 0) { v.x=17.047f; v.y=14.099f; v.z=3.625f;  v.w=16.967f; }
      if (q == 1) { v.x=12.784f; v.y=4.338f;  v.z=15.685f; v.w=12.755f; }
      if (q == 2) { v.x=5.133f; }
    }
    __builtin_nontemporal_store(v, (f32x4*)(orow + 4*q));
  }
}

extern "C" void kernel_launch(void* const* d_in, const int* in_sizes, int n_in,
                              void* d_out, int out_size, void* d_ws, size_t ws_size,
                              hipStream_t stream) {
  const float* phi = (const float*)d_in[0];
  const float* psi = (const float*)d_in[1];
  const float* omg = (const float*)d_in[2];
  const float* bl  = (const float*)d_in[3];
  const float* ba  = (const float*)d_in[4];
  float* out = (float*)d_out;
  const int B = in_sizes[0] / LCH;          // 4096 chains
  hipLaunchKernelGGL(nerf_r12_kernel, dim3(B), dim3(128), 0, stream,
                     phi, psi, omg, bl, ba, out);
}

// Round 7
// 160.122 us; speedup vs baseline: 1.8706x; 1.8706x over previous
//
#include <hip/hip_runtime.h>
#include <math.h>

// Round 13: revert NT stores (R12: 3x write amplification — 144B-stride
// partial-line stores NEED L2 write-combining). Attack the real R10 wall:
// phase serialization (load burst -> compute -> terminal store drain, phases
// ADD because all waves are lockstep single-pass).
//  - Each block processes CPB=2 chains sequentially (grid 2048).
//  - Next chain's 9 dwordx4 loads issue BEFORE current chain's compute
//    (register double-buffer) -> store drain of chain c and load latency of
//    chain c+1 hide under compute of chain c/c+1.
//  - Buffer swap after edge-shfl consumes current inputs: peak liveness ~110.
//  - Extra __syncthreads per iter protects s_tot WAR. No NT, no sched_barrier.
// Compute core identical to R10/R12 (4 res/thread, 2 waves/chain, 12-step
// phase A + 6-level scan + fused replay stores).

#define LCH 512
#define CPB 2

struct Xf { float r[9]; float t[3]; };
struct In9 { float4 ps, om, ph, l0, l1, l2, a0, a1, a2; };

__device__ __forceinline__ Xf xf_compose(const Xf& A, const Xf& B) {
  Xf C;
#pragma unroll
  for (int i = 0; i < 3; ++i) {
    float a0 = A.r[3*i+0], a1 = A.r[3*i+1], a2 = A.r[3*i+2];
    C.r[3*i+0] = a0*B.r[0] + a1*B.r[3] + a2*B.r[6];
    C.r[3*i+1] = a0*B.r[1] + a1*B.r[4] + a2*B.r[7];
    C.r[3*i+2] = a0*B.r[2] + a1*B.r[5] + a2*B.r[8];
    C.t[i]     = a0*B.t[0] + a1*B.t[1] + a2*B.t[2] + A.t[i];
  }
  return C;
}

// P := P o Delta(theta, len, tau), sparsity-aware (~31 FMA).
__device__ __forceinline__ void xf_step(Xf& P, float theta, float len, float tau) {
  float st, ct, sx, cx;
  __sincosf(theta, &st, &ct);
  __sincosf(tau, &sx, &cx);
  float ux = -ct, uy = cx*st, uz = sx*st;      // delta col0 (= d_local / L)
  float v0 = -st, v1 = -ct*cx, v2 = -ct*sx;    // delta col1; col2 = (0,-sx,cx)
  float c00 = P.r[0]*ux + P.r[1]*uy + P.r[2]*uz;
  float c10 = P.r[3]*ux + P.r[4]*uy + P.r[5]*uz;
  float c20 = P.r[6]*ux + P.r[7]*uy + P.r[8]*uz;
  float c01 = P.r[0]*v0 + P.r[1]*v1 + P.r[2]*v2;
  float c11 = P.r[3]*v0 + P.r[4]*v1 + P.r[5]*v2;
  float c21 = P.r[6]*v0 + P.r[7]*v1 + P.r[8]*v2;
  float c02 = P.r[2]*cx - P.r[1]*sx;
  float c12 = P.r[5]*cx - P.r[4]*sx;
  float c22 = P.r[8]*cx - P.r[7]*sx;
  P.t[0] += len*c00; P.t[1] += len*c10; P.t[2] += len*c20;
  P.r[0]=c00; P.r[1]=c01; P.r[2]=c02;
  P.r[3]=c10; P.r[4]=c11; P.r[5]=c12;
  P.r[6]=c20; P.r[7]=c21; P.r[8]=c22;
}

__device__ __forceinline__ void xf_set_delta(Xf& P, float theta, float len, float tau) {
  float st, ct, sx, cx;
  __sincosf(theta, &st, &ct);
  __sincosf(tau, &sx, &cx);
  float ux = -ct, uy = cx*st, uz = sx*st;
  P.r[0]=ux; P.r[1]=-st;    P.r[2]=0.f;
  P.r[3]=uy; P.r[4]=-ct*cx; P.r[5]=-sx;
  P.r[6]=uz; P.r[7]=-ct*sx; P.r[8]=cx;
  P.t[0]=len*ux; P.t[1]=len*uy; P.t[2]=len*uz;
}

__device__ __forceinline__ void xf_identity(Xf& A) {
  A.r[0]=1.f; A.r[1]=0.f; A.r[2]=0.f;
  A.r[3]=0.f; A.r[4]=1.f; A.r[5]=0.f;
  A.r[6]=0.f; A.r[7]=0.f; A.r[8]=1.f;
  A.t[0]=0.f; A.t[1]=0.f; A.t[2]=0.f;
}

__device__ __forceinline__ Xf xf_shfl_up(const Xf& P, int d) {
  Xf O;
#pragma unroll
  for (int i = 0; i < 9; ++i) O.r[i] = __shfl_up(P.r[i], d, 64);
#pragma unroll
  for (int i = 0; i < 3; ++i) O.t[i] = __shfl_up(P.t[i], d, 64);
  return O;
}

__device__ __forceinline__ void load_in(In9& I,
    const float* __restrict__ g_phi, const float* __restrict__ g_psi,
    const float* __restrict__ g_omg, const float* __restrict__ g_bl,
    const float* __restrict__ g_ba, int chain, int j4, int b12) {
  const float* phir = g_phi + (size_t)chain * LCH;
  const float* psir = g_psi + (size_t)chain * LCH;
  const float* omgr = g_omg + (size_t)chain * LCH;
  const float* blr  = g_bl  + (size_t)chain * (LCH*3);
  const float* bar  = g_ba  + (size_t)chain * (LCH*3);
  I.ps = *(const float4*)(psir + j4);
  I.om = *(const float4*)(omgr + j4);
  I.ph = *(const float4*)(phir + j4);
  I.l0 = *(const float4*)(blr + b12);
  I.l1 = *(const float4*)(blr + b12 + 4);
  I.l2 = *(const float4*)(blr + b12 + 8);
  I.a0 = *(const float4*)(bar + b12);
  I.a1 = *(const float4*)(bar + b12 + 4);
  I.a2 = *(const float4*)(bar + b12 + 8);
}

// replay matvec for output float f (0..35) of this thread; f compile-time.
#define REP(f) (A.r[3*((f)%3)+0]*sx[(f)/3] + A.r[3*((f)%3)+1]*sy[(f)/3] \
              + A.r[3*((f)%3)+2]*sz[(f)/3] + A.t[(f)%3])

__global__ __launch_bounds__(128) void nerf_r13_kernel(
    const float* __restrict__ g_phi, const float* __restrict__ g_psi,
    const float* __restrict__ g_omg, const float* __restrict__ g_bl,
    const float* __restrict__ g_ba, float* __restrict__ g_out)
{
  __shared__ float s_tot[12];           // wave-0 inclusive total

  const int t    = threadIdx.x;         // 0..127
  const int lane = t & 63;
  const int wave = t >> 6;
  const int chain0 = blockIdx.x * CPB;

  const int j4  = 4 * t;     // window is residues [4t-1 .. 4t+2]
  const int b12 = 12 * t;

  In9 I;
  load_in(I, g_phi, g_psi, g_omg, g_bl, g_ba, chain0, j4, b12);

#pragma unroll
  for (int c = 0; c < CPB; ++c) {
    const int chain = chain0 + c;
    const float* phir = g_phi + (size_t)chain * LCH;
    const float* psir = g_psi + (size_t)chain * LCH;
    const float* omgr = g_omg + (size_t)chain * LCH;
    const float* blr  = g_bl  + (size_t)chain * (LCH*3);
    const float* bar  = g_ba  + (size_t)chain * (LCH*3);

    // ---- window-edge params from neighbor's tail registers ----
    float psN  = __shfl_up(I.ps.w, 1, 64);   // psi[4t-1]
    float omN  = __shfl_up(I.om.w, 1, 64);   // omg[4t-1]
    float blN0 = __shfl_up(I.l2.y, 1, 64);   // bl[12t-3]
    float blN1 = __shfl_up(I.l2.z, 1, 64);   // bl[12t-2]
    float blN2 = __shfl_up(I.l2.w, 1, 64);   // bl[12t-1]
    float baN0 = __shfl_up(I.a2.y, 1, 64);
    float baN1 = __shfl_up(I.a2.z, 1, 64);
    float baN2 = __shfl_up(I.a2.w, 1, 64);
    if (lane == 0 && t != 0) {               // cross-wave edge (t == 64 only)
      psN  = psir[j4 - 1];
      omN  = omgr[j4 - 1];
      blN0 = blr[b12 - 3]; blN1 = blr[b12 - 2]; blN2 = blr[b12 - 1];
      baN0 = bar[b12 - 3]; baN1 = bar[b12 - 2]; baN2 = bar[b12 - 1];
    }
    // (t==0: edge values junk; they feed only the discarded pre-roll steps)

    float PS[4] = { psN, I.ps.x, I.ps.y, I.ps.z };
    float OM[4] = { omN, I.om.x, I.om.y, I.om.z };
    float PH[4] = { I.ph.x, I.ph.y, I.ph.z, I.ph.w };
    float BL[12] = { blN0, blN1, blN2, I.l0.x, I.l0.y, I.l0.z, I.l0.w,
                     I.l1.x, I.l1.y, I.l1.z, I.l1.w, I.l2.x };
    float BA[12] = { baN0, baN1, baN2, I.a0.x, I.a0.y, I.a0.z, I.a0.w,
                     I.a1.x, I.a1.y, I.a1.z, I.a1.w, I.a2.x };

    // ---- prefetch next chain's inputs (I's float4s now dead) ----
    if (c + 1 < CPB)
      load_in(I, g_phi, g_psi, g_omg, g_bl, g_ba, chain + 1, j4, b12);

    // ---- Phase A: 12 serial steps, stash partial translations ----
    // step a of window residue m: a=0 (N): theta=ba1 L=bl2 tau=psi
    //   a=1 (CA): theta=ba2 L=bl0 tau=omg;  a=2 (C): theta=ba0 L=bl1 tau=phi[r+1]
    Xf P;
    float sx[12], sy[12], sz[12];
#pragma unroll
    for (int k = 0; k < 12; ++k) {
      const int m = k / 3, a = k - 3*m;   // compile-time after unroll
      float th, ln, ta;
      if (a == 0)      { th = BA[3*m+1]; ln = BL[3*m+2]; ta = PS[m]; }
      else if (a == 1) { th = BA[3*m+2]; ln = BL[3*m+0]; ta = OM[m]; }
      else             { th = BA[3*m+0]; ln = BL[3*m+1]; ta = PH[m]; }
      if (k == 0) xf_set_delta(P, th, ln, ta);
      else        xf_step(P, th, ln, ta);
      sx[k] = P.t[0]; sy[k] = P.t[1]; sz[k] = P.t[2];
      if (k == 2 && t == 0) xf_identity(P);  // discard t=0 pre-roll
    }

    // ---- intra-wave inclusive scan (non-commutative) ----
#pragma unroll
    for (int d = 1; d < 64; d <<= 1) {
      Xf O = xf_shfl_up(P, d);
      if (lane >= d) P = xf_compose(O, P);
    }

    // wave-0 total -> LDS for wave 1
    if (wave == 0 && lane == 63) {
#pragma unroll
      for (int i = 0; i < 9; ++i) s_tot[i] = P.r[i];
#pragma unroll
      for (int i = 0; i < 3; ++i) s_tot[9+i] = P.t[i];
    }
    Xf E = xf_shfl_up(P, 1);   // within-wave exclusive (junk for lane 0)
    __syncthreads();

    // ---- prefix transform A = I0 [o W0total] [o E] ----
    Xf A;
    {
      const float ax=17.047f, ay=14.099f, az=3.625f;
      const float bx_=16.967f, by_=12.784f, bz_=4.338f;
      const float cx_=15.685f, cy_=12.755f, cz_=5.133f;
      float abx=bx_-ax, aby=by_-ay, abz=bz_-az;
      float vx=cx_-bx_, vy=cy_-by_, vz=cz_-bz_;
      float vn = sqrtf(vx*vx+vy*vy+vz*vz) + 1e-8f;
      vx/=vn; vy/=vn; vz/=vn;
      float crx = aby*vz - abz*vy;
      float cry = abz*vx - abx*vz;
      float crz = abx*vy - aby*vx;
      float cn = sqrtf(crx*crx+cry*cry+crz*crz) + 1e-8f;
      float nx=crx/cn, ny=cry/cn, nz=crz/cn;
      float mx = ny*vz - nz*vy;
      float my = nz*vx - nx*vz;
      float mz = nx*vy - ny*vx;
      A.r[0]=vx; A.r[1]=mx; A.r[2]=nx;
      A.r[3]=vy; A.r[4]=my; A.r[5]=ny;
      A.r[6]=vz; A.r[7]=mz; A.r[8]=nz;
      A.t[0]=cx_; A.t[1]=cy_; A.t[2]=cz_;
    }
    if (wave == 1) {
      Xf T;
#pragma unroll
      for (int i = 0; i < 9; ++i) T.r[i] = s_tot[i];
#pragma unroll
      for (int i = 0; i < 3; ++i) T.t[i] = s_tot[9+i];
      A = xf_compose(A, T);
    }
    if (lane > 0) A = xf_compose(A, E);

    // ---- fused replay + plain dwordx4 stores (L2 write-combining) ----
    float* orow = g_out + (size_t)chain * 4608 + 36 * t;
#pragma unroll
    for (int q = 0; q < 9; ++q) {
      float4 v;
      v.x = REP(4*q + 0);
      v.y = REP(4*q + 1);
      v.z = REP(4*q + 2);
      v.w = REP(4*q + 3);
      if (t == 0) {   // init block replaces the 3 junk pre-roll atoms (f 0..8)
        if (q == 0) { v.x=17.047f; v.y=14.099f; v.z=3.625f;  v.w=16.967f; }
        if (q == 1) { v.x=12.784f; v.y=4.338f;  v.z=15.685f; v.w=12.755f; }
        if (q == 2) { v.x=5.133f; }
      }
      *(float4*)(orow + 4*q) = v;
    }

    __syncthreads();   // s_tot WAR protection before next iteration's write
  }
}

extern "C" void kernel_launch(void* const* d_in, const int* in_sizes, int n_in,
                              void* d_out, int out_size, void* d_ws, size_t ws_size,
                              hipStream_t stream) {
  const float* phi = (const float*)d_in[0];
  const float* psi = (const float*)d_in[1];
  const float* omg = (const float*)d_in[2];
  const float* bl  = (const float*)d_in[3];
  const float* ba  = (const float*)d_in[4];
  float* out = (float*)d_out;
  const int B = in_sizes[0] / LCH;          // 4096 chains
  hipLaunchKernelGGL(nerf_r13_kernel, dim3(B / CPB), dim3(128), 0, stream,
                     phi, psi, omg, bl, ba, out);
}

// Round 8
// 142.441 us; speedup vs baseline: 2.1028x; 1.1241x over previous
//
#include <hip/hip_runtime.h>
#include <math.h>

// Round 14: decisive test of the store-transaction-width theory.
// R10 lean compute core (4 res/thread, 2 waves/chain, VGPR 52, no spill)
// + LDS-staged epilogue: replay results staged to LDS in linear output
// order, then swept out so each wave store instruction covers 1024B
// contiguous (16 full cache lines) instead of 64 partial lines at 144B
// lane stride. LDS writes: 36-float lane stride (~2-way/phase, free);
// LDS reads: contiguous b128 (conflict-free canonical pattern).
// No NT stores, no sched_barrier, single chain per block.

#define LCH 512

struct Xf { float r[9]; float t[3]; };

__device__ __forceinline__ Xf xf_compose(const Xf& A, const Xf& B) {
  Xf C;
#pragma unroll
  for (int i = 0; i < 3; ++i) {
    float a0 = A.r[3*i+0], a1 = A.r[3*i+1], a2 = A.r[3*i+2];
    C.r[3*i+0] = a0*B.r[0] + a1*B.r[3] + a2*B.r[6];
    C.r[3*i+1] = a0*B.r[1] + a1*B.r[4] + a2*B.r[7];
    C.r[3*i+2] = a0*B.r[2] + a1*B.r[5] + a2*B.r[8];
    C.t[i]     = a0*B.t[0] + a1*B.t[1] + a2*B.t[2] + A.t[i];
  }
  return C;
}

// P := P o Delta(theta, len, tau), sparsity-aware (~31 FMA).
__device__ __forceinline__ void xf_step(Xf& P, float theta, float len, float tau) {
  float st, ct, sx, cx;
  __sincosf(theta, &st, &ct);
  __sincosf(tau, &sx, &cx);
  float ux = -ct, uy = cx*st, uz = sx*st;      // delta col0 (= d_local / L)
  float v0 = -st, v1 = -ct*cx, v2 = -ct*sx;    // delta col1; col2 = (0,-sx,cx)
  float c00 = P.r[0]*ux + P.r[1]*uy + P.r[2]*uz;
  float c10 = P.r[3]*ux + P.r[4]*uy + P.r[5]*uz;
  float c20 = P.r[6]*ux + P.r[7]*uy + P.r[8]*uz;
  float c01 = P.r[0]*v0 + P.r[1]*v1 + P.r[2]*v2;
  float c11 = P.r[3]*v0 + P.r[4]*v1 + P.r[5]*v2;
  float c21 = P.r[6]*v0 + P.r[7]*v1 + P.r[8]*v2;
  float c02 = P.r[2]*cx - P.r[1]*sx;
  float c12 = P.r[5]*cx - P.r[4]*sx;
  float c22 = P.r[8]*cx - P.r[7]*sx;
  P.t[0] += len*c00; P.t[1] += len*c10; P.t[2] += len*c20;
  P.r[0]=c00; P.r[1]=c01; P.r[2]=c02;
  P.r[3]=c10; P.r[4]=c11; P.r[5]=c12;
  P.r[6]=c20; P.r[7]=c21; P.r[8]=c22;
}

__device__ __forceinline__ void xf_set_delta(Xf& P, float theta, float len, float tau) {
  float st, ct, sx, cx;
  __sincosf(theta, &st, &ct);
  __sincosf(tau, &sx, &cx);
  float ux = -ct, uy = cx*st, uz = sx*st;
  P.r[0]=ux; P.r[1]=-st;    P.r[2]=0.f;
  P.r[3]=uy; P.r[4]=-ct*cx; P.r[5]=-sx;
  P.r[6]=uz; P.r[7]=-ct*sx; P.r[8]=cx;
  P.t[0]=len*ux; P.t[1]=len*uy; P.t[2]=len*uz;
}

__device__ __forceinline__ void xf_identity(Xf& A) {
  A.r[0]=1.f; A.r[1]=0.f; A.r[2]=0.f;
  A.r[3]=0.f; A.r[4]=1.f; A.r[5]=0.f;
  A.r[6]=0.f; A.r[7]=0.f; A.r[8]=1.f;
  A.t[0]=0.f; A.t[1]=0.f; A.t[2]=0.f;
}

__device__ __forceinline__ Xf xf_shfl_up(const Xf& P, int d) {
  Xf O;
#pragma unroll
  for (int i = 0; i < 9; ++i) O.r[i] = __shfl_up(P.r[i], d, 64);
#pragma unroll
  for (int i = 0; i < 3; ++i) O.t[i] = __shfl_up(P.t[i], d, 64);
  return O;
}

// replay matvec for output float f (0..35) of this thread; f compile-time.
#define REP(f) (A.r[3*((f)%3)+0]*sx[(f)/3] + A.r[3*((f)%3)+1]*sy[(f)/3] \
              + A.r[3*((f)%3)+2]*sz[(f)/3] + A.t[(f)%3])

__global__ __launch_bounds__(128) void nerf_r14_kernel(
    const float* __restrict__ g_phi, const float* __restrict__ g_psi,
    const float* __restrict__ g_omg, const float* __restrict__ g_bl,
    const float* __restrict__ g_ba, float* __restrict__ g_out)
{
  __shared__ float s_tot[12];           // wave-0 inclusive total
  __shared__ float s_out[4608];         // linear output-order staging (18 KB)

  const int t    = threadIdx.x;         // 0..127
  const int lane = t & 63;
  const int wave = t >> 6;
  const int chain = blockIdx.x;

  const float* phir = g_phi + (size_t)chain * LCH;
  const float* psir = g_psi + (size_t)chain * LCH;
  const float* omgr = g_omg + (size_t)chain * LCH;
  const float* blr  = g_bl  + (size_t)chain * (LCH*3);
  const float* bar  = g_ba  + (size_t)chain * (LCH*3);

  const int j4  = 4 * t;     // window is residues [4t-1 .. 4t+2]
  const int b12 = 12 * t;

  // ---- 9 aligned dwordx4 loads per thread ----
  float4 vps = *(const float4*)(psir + j4);      // psi[4t .. 4t+3]
  float4 vom = *(const float4*)(omgr + j4);      // omg[4t .. 4t+3]
  float4 vph = *(const float4*)(phir + j4);      // phi[4t .. 4t+3] (phi[r+1] set)
  float4 l0  = *(const float4*)(blr + b12);      // bl[12t   .. 12t+3]
  float4 l1  = *(const float4*)(blr + b12 + 4);  // bl[12t+4 .. 12t+7]
  float4 l2  = *(const float4*)(blr + b12 + 8);  // bl[12t+8 .. 12t+11]
  float4 a0  = *(const float4*)(bar + b12);
  float4 a1  = *(const float4*)(bar + b12 + 4);
  float4 a2  = *(const float4*)(bar + b12 + 8);

  // ---- window-edge params from neighbor's tail registers ----
  float psN  = __shfl_up(vps.w, 1, 64);   // psi[4t-1]
  float omN  = __shfl_up(vom.w, 1, 64);   // omg[4t-1]
  float blN0 = __shfl_up(l2.y, 1, 64);    // bl[12t-3]
  float blN1 = __shfl_up(l2.z, 1, 64);    // bl[12t-2]
  float blN2 = __shfl_up(l2.w, 1, 64);    // bl[12t-1]
  float baN0 = __shfl_up(a2.y, 1, 64);
  float baN1 = __shfl_up(a2.z, 1, 64);
  float baN2 = __shfl_up(a2.w, 1, 64);
  if (lane == 0 && t != 0) {              // cross-wave edge (t == 64 only)
    psN  = psir[j4 - 1];
    omN  = omgr[j4 - 1];
    blN0 = blr[b12 - 3]; blN1 = blr[b12 - 2]; blN2 = blr[b12 - 1];
    baN0 = bar[b12 - 3]; baN1 = bar[b12 - 2]; baN2 = bar[b12 - 1];
  }
  // (t==0: edge values are junk; they feed only the discarded pre-roll steps)

  float PS[4] = { psN, vps.x, vps.y, vps.z };
  float OM[4] = { omN, vom.x, vom.y, vom.z };
  float PH[4] = { vph.x, vph.y, vph.z, vph.w };
  float BL[12] = { blN0, blN1, blN2, l0.x, l0.y, l0.z, l0.w,
                   l1.x, l1.y, l1.z, l1.w, l2.x };
  float BA[12] = { baN0, baN1, baN2, a0.x, a0.y, a0.z, a0.w,
                   a1.x, a1.y, a1.z, a1.w, a2.x };

  // ---- Phase A: 12 serial steps, stash partial translations ----
  // step a of window residue m: a=0 (N): theta=ba1 L=bl2 tau=psi
  //   a=1 (CA): theta=ba2 L=bl0 tau=omega;  a=2 (C): theta=ba0 L=bl1 tau=phi[r+1]
  Xf P;
  float sx[12], sy[12], sz[12];
#pragma unroll
  for (int k = 0; k < 12; ++k) {
    const int m = k / 3, a = k - 3*m;   // compile-time after unroll
    float th, ln, ta;
    if (a == 0)      { th = BA[3*m+1]; ln = BL[3*m+2]; ta = PS[m]; }
    else if (a == 1) { th = BA[3*m+2]; ln = BL[3*m+0]; ta = OM[m]; }
    else             { th = BA[3*m+0]; ln = BL[3*m+1]; ta = PH[m]; }
    if (k == 0) xf_set_delta(P, th, ln, ta);
    else        xf_step(P, th, ln, ta);
    sx[k] = P.t[0]; sy[k] = P.t[1]; sz[k] = P.t[2];
    if (k == 2 && t == 0) xf_identity(P);  // discard t=0 pre-roll
  }

  // ---- intra-wave inclusive scan (non-commutative) ----
#pragma unroll
  for (int d = 1; d < 64; d <<= 1) {
    Xf O = xf_shfl_up(P, d);
    if (lane >= d) P = xf_compose(O, P);
  }

  // wave-0 total -> LDS for wave 1
  if (wave == 0 && lane == 63) {
#pragma unroll
    for (int i = 0; i < 9; ++i) s_tot[i] = P.r[i];
#pragma unroll
    for (int i = 0; i < 3; ++i) s_tot[9+i] = P.t[i];
  }
  Xf E = xf_shfl_up(P, 1);   // within-wave exclusive (junk for lane 0)
  __syncthreads();

  // ---- prefix transform A = I0 [o W0total] [o E] ----
  Xf A;
  {
    const float ax=17.047f, ay=14.099f, az=3.625f;
    const float bx_=16.967f, by_=12.784f, bz_=4.338f;
    const float cx_=15.685f, cy_=12.755f, cz_=5.133f;
    float abx=bx_-ax, aby=by_-ay, abz=bz_-az;
    float vx=cx_-bx_, vy=cy_-by_, vz=cz_-bz_;
    float vn = sqrtf(vx*vx+vy*vy+vz*vz) + 1e-8f;
    vx/=vn; vy/=vn; vz/=vn;
    float crx = aby*vz - abz*vy;
    float cry = abz*vx - abx*vz;
    float crz = abx*vy - aby*vx;
    float cn = sqrtf(crx*crx+cry*cry+crz*crz) + 1e-8f;
    float nx=crx/cn, ny=cry/cn, nz=crz/cn;
    float mx = ny*vz - nz*vy;
    float my = nz*vx - nx*vz;
    float mz = nx*vy - ny*vx;
    A.r[0]=vx; A.r[1]=mx; A.r[2]=nx;
    A.r[3]=vy; A.r[4]=my; A.r[5]=ny;
    A.r[6]=vz; A.r[7]=mz; A.r[8]=nz;
    A.t[0]=cx_; A.t[1]=cy_; A.t[2]=cz_;
  }
  if (wave == 1) {
    Xf T;
#pragma unroll
    for (int i = 0; i < 9; ++i) T.r[i] = s_tot[i];
#pragma unroll
    for (int i = 0; i < 3; ++i) T.t[i] = s_tot[9+i];
    A = xf_compose(A, T);
  }
  if (lane > 0) A = xf_compose(A, E);

  // ---- replay -> LDS staging (linear output order) ----
  // thread t owns output floats [36t, 36t+36); LDS index == output index.
#pragma unroll
  for (int q = 0; q < 9; ++q) {
    float4 v;
    v.x = REP(4*q + 0);
    v.y = REP(4*q + 1);
    v.z = REP(4*q + 2);
    v.w = REP(4*q + 3);
    if (t == 0) {   // init block replaces the 3 junk pre-roll atoms (f 0..8)
      if (q == 0) { v.x=17.047f; v.y=14.099f; v.z=3.625f;  v.w=16.967f; }
      if (q == 1) { v.x=12.784f; v.y=4.338f;  v.z=15.685f; v.w=12.755f; }
      if (q == 2) { v.x=5.133f; }
    }
    *(float4*)(s_out + 36*t + 4*q) = v;
  }
  __syncthreads();

  // ---- coalesced sweep: per wave store instruction = 1024B contiguous ----
  float* orow = g_out + (size_t)chain * 4608;
#pragma unroll
  for (int p = 0; p < 9; ++p) {
    const int g = 512*p + 4*t;
    float4 v = *(const float4*)(s_out + g);   // contiguous b128, conflict-free
    *(float4*)(orow + g) = v;                 // 64 lanes x 16B = 16 full lines
  }
}

extern "C" void kernel_launch(void* const* d_in, const int* in_sizes, int n_in,
                              void* d_out, int out_size, void* d_ws, size_t ws_size,
                              hipStream_t stream) {
  const float* phi = (const float*)d_in[0];
  const float* psi = (const float*)d_in[1];
  const float* omg = (const float*)d_in[2];
  const float* bl  = (const float*)d_in[3];
  const float* ba  = (const float*)d_in[4];
  float* out = (float*)d_out;
  const int B = in_sizes[0] / LCH;          // 4096 chains
  hipLaunchKernelGGL(nerf_r14_kernel, dim3(B), dim3(128), 0, stream,
                     phi, psi, omg, bl, ba, out);
}

// Round 9
// 141.104 us; speedup vs baseline: 2.1227x; 1.0095x over previous
//
#include <hip/hip_runtime.h>
#include <math.h>

// Round 15: attack the per-wave LATENCY chain (the R14 synthesis: duration is
// invariant to traffic 113->153MB => NOT BW-bound; VALUBusy 25% => ~14us of
// issue in a 57us kernel => latency-bound on dependency chains).
// Phase A was 12 strictly serial xf_steps (2 sincos + 3-deep FMA chain each).
// Split it into TWO independent 6-step half-products interleaved in one
// unrolled loop (2x ILP on the longest pure-dependency segment):
//   P0 = D0..D5 (stash running t), Q = D6..D11 (stash running t)
//   P  = P0 o Q  (one extra compose)
//   replay: floats 0..17 via A, floats 18..35 via A2 = A o P0.
// Everything else identical to R14 (9x dwordx4 loads + edge shfl, 6-level
// scan, wave0-total LDS fixup, LDS-staged contiguous store sweep).

#define LCH 512

struct Xf { float r[9]; float t[3]; };

__device__ __forceinline__ Xf xf_compose(const Xf& A, const Xf& B) {
  Xf C;
#pragma unroll
  for (int i = 0; i < 3; ++i) {
    float a0 = A.r[3*i+0], a1 = A.r[3*i+1], a2 = A.r[3*i+2];
    C.r[3*i+0] = a0*B.r[0] + a1*B.r[3] + a2*B.r[6];
    C.r[3*i+1] = a0*B.r[1] + a1*B.r[4] + a2*B.r[7];
    C.r[3*i+2] = a0*B.r[2] + a1*B.r[5] + a2*B.r[8];
    C.t[i]     = a0*B.t[0] + a1*B.t[1] + a2*B.t[2] + A.t[i];
  }
  return C;
}

// P := P o Delta(theta, len, tau), sparsity-aware (~31 FMA).
__device__ __forceinline__ void xf_step(Xf& P, float theta, float len, float tau) {
  float st, ct, sx, cx;
  __sincosf(theta, &st, &ct);
  __sincosf(tau, &sx, &cx);
  float ux = -ct, uy = cx*st, uz = sx*st;      // delta col0 (= d_local / L)
  float v0 = -st, v1 = -ct*cx, v2 = -ct*sx;    // delta col1; col2 = (0,-sx,cx)
  float c00 = P.r[0]*ux + P.r[1]*uy + P.r[2]*uz;
  float c10 = P.r[3]*ux + P.r[4]*uy + P.r[5]*uz;
  float c20 = P.r[6]*ux + P.r[7]*uy + P.r[8]*uz;
  float c01 = P.r[0]*v0 + P.r[1]*v1 + P.r[2]*v2;
  float c11 = P.r[3]*v0 + P.r[4]*v1 + P.r[5]*v2;
  float c21 = P.r[6]*v0 + P.r[7]*v1 + P.r[8]*v2;
  float c02 = P.r[2]*cx - P.r[1]*sx;
  float c12 = P.r[5]*cx - P.r[4]*sx;
  float c22 = P.r[8]*cx - P.r[7]*sx;
  P.t[0] += len*c00; P.t[1] += len*c10; P.t[2] += len*c20;
  P.r[0]=c00; P.r[1]=c01; P.r[2]=c02;
  P.r[3]=c10; P.r[4]=c11; P.r[5]=c12;
  P.r[6]=c20; P.r[7]=c21; P.r[8]=c22;
}

__device__ __forceinline__ void xf_set_delta(Xf& P, float theta, float len, float tau) {
  float st, ct, sx, cx;
  __sincosf(theta, &st, &ct);
  __sincosf(tau, &sx, &cx);
  float ux = -ct, uy = cx*st, uz = sx*st;
  P.r[0]=ux; P.r[1]=-st;    P.r[2]=0.f;
  P.r[3]=uy; P.r[4]=-ct*cx; P.r[5]=-sx;
  P.r[6]=uz; P.r[7]=-ct*sx; P.r[8]=cx;
  P.t[0]=len*ux; P.t[1]=len*uy; P.t[2]=len*uz;
}

__device__ __forceinline__ void xf_identity(Xf& A) {
  A.r[0]=1.f; A.r[1]=0.f; A.r[2]=0.f;
  A.r[3]=0.f; A.r[4]=1.f; A.r[5]=0.f;
  A.r[6]=0.f; A.r[7]=0.f; A.r[8]=1.f;
  A.t[0]=0.f; A.t[1]=0.f; A.t[2]=0.f;
}

__device__ __forceinline__ Xf xf_shfl_up(const Xf& P, int d) {
  Xf O;
#pragma unroll
  for (int i = 0; i < 9; ++i) O.r[i] = __shfl_up(P.r[i], d, 64);
#pragma unroll
  for (int i = 0; i < 3; ++i) O.t[i] = __shfl_up(P.t[i], d, 64);
  return O;
}

// replay matvec for output float f (0..35); f compile-time under unroll.
// f<18: prefix A applied to first-half stash; f>=18: prefix A2 = A o P0
// applied to Q's own stash.
#define REPF(f) ((f) < 18 ? \
    (A.r[3*((f)%3)+0]*sx0[(f)/3] + A.r[3*((f)%3)+1]*sy0[(f)/3] \
   + A.r[3*((f)%3)+2]*sz0[(f)/3] + A.t[(f)%3]) : \
    (A2.r[3*((f)%3)+0]*qx[(f)/3-6] + A2.r[3*((f)%3)+1]*qy[(f)/3-6] \
   + A2.r[3*((f)%3)+2]*qz[(f)/3-6] + A2.t[(f)%3]))

__global__ __launch_bounds__(128) void nerf_r15_kernel(
    const float* __restrict__ g_phi, const float* __restrict__ g_psi,
    const float* __restrict__ g_omg, const float* __restrict__ g_bl,
    const float* __restrict__ g_ba, float* __restrict__ g_out)
{
  __shared__ float s_tot[12];           // wave-0 inclusive total
  __shared__ float s_out[4608];         // linear output-order staging (18 KB)

  const int t    = threadIdx.x;         // 0..127
  const int lane = t & 63;
  const int wave = t >> 6;
  const int chain = blockIdx.x;

  const float* phir = g_phi + (size_t)chain * LCH;
  const float* psir = g_psi + (size_t)chain * LCH;
  const float* omgr = g_omg + (size_t)chain * LCH;
  const float* blr  = g_bl  + (size_t)chain * (LCH*3);
  const float* bar  = g_ba  + (size_t)chain * (LCH*3);

  const int j4  = 4 * t;     // window is residues [4t-1 .. 4t+2]
  const int b12 = 12 * t;

  // ---- 9 aligned dwordx4 loads per thread ----
  float4 vps = *(const float4*)(psir + j4);
  float4 vom = *(const float4*)(omgr + j4);
  float4 vph = *(const float4*)(phir + j4);
  float4 l0  = *(const float4*)(blr + b12);
  float4 l1  = *(const float4*)(blr + b12 + 4);
  float4 l2  = *(const float4*)(blr + b12 + 8);
  float4 a0  = *(const float4*)(bar + b12);
  float4 a1  = *(const float4*)(bar + b12 + 4);
  float4 a2  = *(const float4*)(bar + b12 + 8);

  // ---- window-edge params from neighbor's tail registers ----
  float psN  = __shfl_up(vps.w, 1, 64);
  float omN  = __shfl_up(vom.w, 1, 64);
  float blN0 = __shfl_up(l2.y, 1, 64);
  float blN1 = __shfl_up(l2.z, 1, 64);
  float blN2 = __shfl_up(l2.w, 1, 64);
  float baN0 = __shfl_up(a2.y, 1, 64);
  float baN1 = __shfl_up(a2.z, 1, 64);
  float baN2 = __shfl_up(a2.w, 1, 64);
  if (lane == 0 && t != 0) {              // cross-wave edge (t == 64 only)
    psN  = psir[j4 - 1];
    omN  = omgr[j4 - 1];
    blN0 = blr[b12 - 3]; blN1 = blr[b12 - 2]; blN2 = blr[b12 - 1];
    baN0 = bar[b12 - 3]; baN1 = bar[b12 - 2]; baN2 = bar[b12 - 1];
  }
  // (t==0: edge values are junk; they feed only the discarded pre-roll steps)

  float PS[4] = { psN, vps.x, vps.y, vps.z };
  float OM[4] = { omN, vom.x, vom.y, vom.z };
  float PH[4] = { vph.x, vph.y, vph.z, vph.w };
  float BL[12] = { blN0, blN1, blN2, l0.x, l0.y, l0.z, l0.w,
                   l1.x, l1.y, l1.z, l1.w, l2.x };
  float BA[12] = { baN0, baN1, baN2, a0.x, a0.y, a0.z, a0.w,
                   a1.x, a1.y, a1.z, a1.w, a2.x };

  // ---- Phase A: two independent 6-step chains, interleaved (2x ILP) ----
  // step a of window residue m: a=0 (N): theta=ba1 L=bl2 tau=psi
  //   a=1 (CA): theta=ba2 L=bl0 tau=omega;  a=2 (C): theta=ba0 L=bl1 tau=phi[r+1]
  Xf P0, Q;
  float sx0[6], sy0[6], sz0[6], qx[6], qy[6], qz[6];
#pragma unroll
  for (int k = 0; k < 6; ++k) {
    // chain 0: step k (residues m=0..1)
    {
      const int m = k / 3, a = k - 3*m;
      float th, ln, ta;
      if (a == 0)      { th = BA[3*m+1]; ln = BL[3*m+2]; ta = PS[m]; }
      else if (a == 1) { th = BA[3*m+2]; ln = BL[3*m+0]; ta = OM[m]; }
      else             { th = BA[3*m+0]; ln = BL[3*m+1]; ta = PH[m]; }
      if (k == 0) xf_set_delta(P0, th, ln, ta);
      else        xf_step(P0, th, ln, ta);
      sx0[k] = P0.t[0]; sy0[k] = P0.t[1]; sz0[k] = P0.t[2];
      if (k == 2 && t == 0) xf_identity(P0);  // discard t=0 pre-roll
    }
    // chain 1: step k+6 (residues m=2..3) — independent of chain 0
    {
      const int kk = k + 6;
      const int m = kk / 3, a = kk - 3*m;
      float th, ln, ta;
      if (a == 0)      { th = BA[3*m+1]; ln = BL[3*m+2]; ta = PS[m]; }
      else if (a == 1) { th = BA[3*m+2]; ln = BL[3*m+0]; ta = OM[m]; }
      else             { th = BA[3*m+0]; ln = BL[3*m+1]; ta = PH[m]; }
      if (k == 0) xf_set_delta(Q, th, ln, ta);
      else        xf_step(Q, th, ln, ta);
      qx[k] = Q.t[0]; qy[k] = Q.t[1]; qz[k] = Q.t[2];
    }
  }
  Xf P = xf_compose(P0, Q);   // full 12-step product

  // ---- intra-wave inclusive scan (non-commutative) ----
#pragma unroll
  for (int d = 1; d < 64; d <<= 1) {
    Xf O = xf_shfl_up(P, d);
    if (lane >= d) P = xf_compose(O, P);
  }

  // wave-0 total -> LDS for wave 1
  if (wave == 0 && lane == 63) {
#pragma unroll
    for (int i = 0; i < 9; ++i) s_tot[i] = P.r[i];
#pragma unroll
    for (int i = 0; i < 3; ++i) s_tot[9+i] = P.t[i];
  }
  Xf E = xf_shfl_up(P, 1);   // within-wave exclusive (junk for lane 0)
  __syncthreads();

  // ---- prefix transform A = I0 [o W0total] [o E] ----
  Xf A;
  {
    const float ax=17.047f, ay=14.099f, az=3.625f;
    const float bx_=16.967f, by_=12.784f, bz_=4.338f;
    const float cx_=15.685f, cy_=12.755f, cz_=5.133f;
    float abx=bx_-ax, aby=by_-ay, abz=bz_-az;
    float vx=cx_-bx_, vy=cy_-by_, vz=cz_-bz_;
    float vn = sqrtf(vx*vx+vy*vy+vz*vz) + 1e-8f;
    vx/=vn; vy/=vn; vz/=vn;
    float crx = aby*vz - abz*vy;
    float cry = abz*vx - abx*vz;
    float crz = abx*vy - aby*vx;
    float cn = sqrtf(crx*crx+cry*cry+crz*crz) + 1e-8f;
    float nx=crx/cn, ny=cry/cn, nz=crz/cn;
    float mx = ny*vz - nz*vy;
    float my = nz*vx - nx*vz;
    float mz = nx*vy - ny*vx;
    A.r[0]=vx; A.r[1]=mx; A.r[2]=nx;
    A.r[3]=vy; A.r[4]=my; A.r[5]=ny;
    A.r[6]=vz; A.r[7]=mz; A.r[8]=nz;
    A.t[0]=cx_; A.t[1]=cy_; A.t[2]=cz_;
  }
  if (wave == 1) {
    Xf T;
#pragma unroll
    for (int i = 0; i < 9; ++i) T.r[i] = s_tot[i];
#pragma unroll
    for (int i = 0; i < 3; ++i) T.t[i] = s_tot[9+i];
    A = xf_compose(A, T);
  }
  if (lane > 0) A = xf_compose(A, E);

  Xf A2 = xf_compose(A, P0);   // prefix for the second half-window

  // ---- replay -> LDS staging (linear output order) ----
#pragma unroll
  for (int q = 0; q < 9; ++q) {
    float4 v;
    v.x = REPF(4*q + 0);
    v.y = REPF(4*q + 1);
    v.z = REPF(4*q + 2);
    v.w = REPF(4*q + 3);
    if (t == 0) {   // init block replaces the 3 junk pre-roll atoms (f 0..8)
      if (q == 0) { v.x=17.047f; v.y=14.099f; v.z=3.625f;  v.w=16.967f; }
      if (q == 1) { v.x=12.784f; v.y=4.338f;  v.z=15.685f; v.w=12.755f; }
      if (q == 2) { v.x=5.133f; }
    }
    *(float4*)(s_out + 36*t + 4*q) = v;
  }
  __syncthreads();

  // ---- coalesced sweep: per wave store instruction = 1024B contiguous ----
  float* orow = g_out + (size_t)chain * 4608;
#pragma unroll
  for (int p = 0; p < 9; ++p) {
    const int g = 512*p + 4*t;
    float4 v = *(const float4*)(s_out + g);
    *(float4*)(orow + g) = v;
  }
}

extern "C" void kernel_launch(void* const* d_in, const int* in_sizes, int n_in,
                              void* d_out, int out_size, void* d_ws, size_t ws_size,
                              hipStream_t stream) {
  const float* phi = (const float*)d_in[0];
  const float* psi = (const float*)d_in[1];
  const float* omg = (const float*)d_in[2];
  const float* bl  = (const float*)d_in[3];
  const float* ba  = (const float*)d_in[4];
  float* out = (float*)d_out;
  const int B = in_sizes[0] / LCH;          // 4096 chains
  hipLaunchKernelGGL(nerf_r15_kernel, dim3(B), dim3(128), 0, stream,
                     phi, psi, omg, bl, ba, out);
}